// Round 24
// baseline (550.700 us; speedup 1.0000x reference)
//
#include <hip/hip_runtime.h>

// ADDA local attention, K=3, dilation=1, head_dim=64.
// q,k,v = [B=8, d=512, H=56, W=56] fp32 (channel-major), out = [B,H,W,512] fp32.
//
// R24: producer/consumer wave split at CONSTANT total loads (the one
// untried structural point; every prior TLP attempt also added loads).
//  wave0 = R17 pass-1 verbatim (4 k rows + 2 q rows, 16x 4-ch slabs,
//          3-deep), softmax, writes 18 weights/px to LDS, barrier, exits.
//  wave1 = issues 3 v-slabs BEFORE the barrier (48 loads in flight during
//          all of pass-1), then R17 pass-2 verbatim (transpose + READOUT,
//          full 512B output ownership).
//  -> 640 VMEM/block exactly as R17, but ~2x in-flight loads per CU.
// Weights alias tbuf: wave1 reads them into registers before its first
// transpose write (same-wave LDS ordering + the single barrier).

namespace {

constexpr int HD = 64, HH = 56, WW = 56, HW = HH * WW;
constexpr int CS = HW, DTOT = 512;
constexpr float SCALE = 0.125f;
constexpr int NP   = HH / 2;   // 28 row-pairs
constexpr int TSTR = 36;       // px stride in transpose LDS

// value of this row at x-1 (lane i <- lane i-1): wave_shr:1 = 0x138
__device__ __forceinline__ float tapL(float v) {
  int i = __float_as_int(v);
  return __int_as_float(__builtin_amdgcn_update_dpp(i, i, 0x138, 0xF, 0xF, false));
}
// value of this row at x+1 (lane i <- lane i+1): wave_shl:1 = 0x130
__device__ __forceinline__ float tapR(float v) {
  int i = __float_as_int(v);
  return __int_as_float(__builtin_amdgcn_update_dpp(i, i, 0x130, 0xF, 0xF, false));
}

__global__ __launch_bounds__(128, 2)
void adda_fwd(const float* __restrict__ qg, const float* __restrict__ kg,
              const float* __restrict__ vg, float* __restrict__ outg) {
  __shared__ float tbuf[128 * TSTR];   // 18432 B; floats [0,1008) also carry
                                       // the 56x18 weight block across the barrier

  // XCD-aware bijective swizzle (nwg = 1792 = 8*224)
  int wg = (int)blockIdx.x;
  const int nwg = (int)gridDim.x;
  if ((nwg & 7) == 0) wg = (wg & 7) * (nwg >> 3) + (wg >> 3);

  const int pair = wg % NP;
  const int bh   = wg / NP;              // b*8 + head
  const int l    = (int)threadIdx.x & 63;
  const int wv   = (int)threadIdx.x >> 6;  // 0 = producer, 1 = consumer
  const int y    = pair * 2;             // rows y, y+1
  const int x    = l < WW ? l : WW - 1;  // lanes 56-63 clone x=55 (not stored)

  const long base = (long)bh * HD * HW;
  const int gy0 = (y > 0) ? y - 1 : 0;          // clamped; masked below
  const int gy3 = (y + 2 < HH) ? y + 2 : HH - 1;

  // ================= producer: pass 1 (k, q) =================
  if (wv == 0) {
    const float* __restrict__ qp0 = qg + base + (long)y * WW + x;
    const float* __restrict__ qp1 = qg + base + (long)(y + 1) * WW + x;
    const float* __restrict__ k0p = kg + base + (long)gy0 * WW + x;
    const float* __restrict__ k1p = kg + base + (long)y * WW + x;
    const float* __restrict__ k2p = kg + base + (long)(y + 1) * WW + x;
    const float* __restrict__ k3p = kg + base + (long)gy3 * WW + x;

    float lg[18];
#pragma unroll
    for (int n = 0; n < 18; ++n) lg[n] = 0.f;

    float q0A[4], q1A[4], a0A[4], a1A[4], a2A[4], a3A[4];
    float q0B[4], q1B[4], a0B[4], a1B[4], a2B[4], a3B[4];
    float q0C[4], q1C[4], a0C[4], a1C[4], a2C[4], a3C[4];

#define LOADK(S, cb)                                    \
  _Pragma("unroll") for (int i = 0; i < 4; ++i) {       \
    q0##S[i] = qp0[((cb) + i) * CS];                    \
    q1##S[i] = qp1[((cb) + i) * CS];                    \
    a0##S[i] = k0p[((cb) + i) * CS];                    \
    a1##S[i] = k1p[((cb) + i) * CS];                    \
    a2##S[i] = k2p[((cb) + i) * CS];                    \
    a3##S[i] = k3p[((cb) + i) * CS];                    \
  }
#define CONSK(S)                                        \
  _Pragma("unroll") for (int i = 0; i < 4; ++i) {       \
    const float t0l = tapL(a0##S[i]), t0r = tapR(a0##S[i]); \
    const float t1l = tapL(a1##S[i]), t1r = tapR(a1##S[i]); \
    const float t2l = tapL(a2##S[i]), t2r = tapR(a2##S[i]); \
    const float t3l = tapL(a3##S[i]), t3r = tapR(a3##S[i]); \
    const float q0 = q0##S[i], q1 = q1##S[i];           \
    lg[0]  = fmaf(q0, t0l,      lg[0]);                 \
    lg[1]  = fmaf(q0, a0##S[i], lg[1]);                 \
    lg[2]  = fmaf(q0, t0r,      lg[2]);                 \
    lg[3]  = fmaf(q0, t1l,      lg[3]);                 \
    lg[4]  = fmaf(q0, a1##S[i], lg[4]);                 \
    lg[5]  = fmaf(q0, t1r,      lg[5]);                 \
    lg[6]  = fmaf(q0, t2l,      lg[6]);                 \
    lg[7]  = fmaf(q0, a2##S[i], lg[7]);                 \
    lg[8]  = fmaf(q0, t2r,      lg[8]);                 \
    lg[9]  = fmaf(q1, t1l,      lg[9]);                 \
    lg[10] = fmaf(q1, a1##S[i], lg[10]);                \
    lg[11] = fmaf(q1, t1r,      lg[11]);                \
    lg[12] = fmaf(q1, t2l,      lg[12]);                \
    lg[13] = fmaf(q1, a2##S[i], lg[13]);                \
    lg[14] = fmaf(q1, t2r,      lg[14]);                \
    lg[15] = fmaf(q1, t3l,      lg[15]);                \
    lg[16] = fmaf(q1, a3##S[i], lg[16]);                \
    lg[17] = fmaf(q1, t3r,      lg[17]);                \
  }

    LOADK(A, 0); LOADK(B, 4); LOADK(C, 8);
    CONSK(A); LOADK(A, 12);
    CONSK(B); LOADK(B, 16);
    CONSK(C); LOADK(C, 20);
    CONSK(A); LOADK(A, 24);
    CONSK(B); LOADK(B, 28);
    CONSK(C); LOADK(C, 32);
    CONSK(A); LOADK(A, 36);
    CONSK(B); LOADK(B, 40);
    CONSK(C); LOADK(C, 44);
    CONSK(A); LOADK(A, 48);
    CONSK(B); LOADK(B, 52);
    CONSK(C); LOADK(C, 56);
    CONSK(A); LOADK(A, 60);
    CONSK(B);
    CONSK(C);
    CONSK(A);

    // softmax, both rows (zero-padded unfold: OOB logit = exact 0)
    const bool okl = x > 0, okr = x < WW - 1;
    const bool okt0 = y > 0;
    const bool okb1 = (y + 2) < HH;
    const bool ok[18] = {
      okt0 && okl, okt0, okt0 && okr,
      okl,         true, okr,
      okl,         true, okr,
      okl,         true, okr,
      okl,         true, okr,
      okb1 && okl, okb1, okb1 && okr};
    float w[18];
#pragma unroll
    for (int e = 0; e < 2; ++e) {
      float mx = 0.f;
#pragma unroll
      for (int n = 0; n < 9; ++n) {
        w[e * 9 + n] = ok[e * 9 + n] ? lg[e * 9 + n] * SCALE : 0.f;
        mx = fmaxf(mx, w[e * 9 + n]);
      }
      float sum = 0.f;
#pragma unroll
      for (int n = 0; n < 9; ++n) { w[e * 9 + n] = __expf(w[e * 9 + n] - mx); sum += w[e * 9 + n]; }
      const float inv = 1.f / sum;
#pragma unroll
      for (int n = 0; n < 9; ++n)
        w[e * 9 + n] = ok[e * 9 + n] ? w[e * 9 + n] * inv : 0.f;  // OOB v = 0
    }

    // hand weights to the consumer (floats [0, 56*18))
    if (l < WW) {
#pragma unroll
      for (int n = 0; n < 18; ++n) tbuf[l * 18 + n] = w[n];
    }
    __syncthreads();
    return;   // producer done; slot frees for other blocks
  }

  // ================= consumer: pass 2 (v) =================
  const float* __restrict__ v0p = vg + base + (long)gy0 * WW + x;
  const float* __restrict__ v1p = vg + base + (long)y * WW + x;
  const float* __restrict__ v2p = vg + base + (long)(y + 1) * WW + x;
  const float* __restrict__ v3p = vg + base + (long)gy3 * WW + x;

  float b0A[4], b1A[4], b2A[4], b3A[4];
  float b0B[4], b1B[4], b2B[4], b3B[4];
  float b0C[4], b1C[4], b2C[4], b3C[4];
#define LOADV(S, cb)                                    \
  _Pragma("unroll") for (int i = 0; i < 4; ++i) {       \
    b0##S[i] = v0p[((cb) + i) * CS];                    \
    b1##S[i] = v1p[((cb) + i) * CS];                    \
    b2##S[i] = v2p[((cb) + i) * CS];                    \
    b3##S[i] = v3p[((cb) + i) * CS];                    \
  }

  // issue 3 slabs now: 48 loads in flight during the producer's pass-1
  LOADV(A, 0); LOADV(B, 4); LOADV(C, 8);
  __syncthreads();

  // read weights into registers BEFORE any transpose write (same-wave order)
  float w[18];
#pragma unroll
  for (int n = 0; n < 18; ++n) w[n] = tbuf[x * 18 + n];

  float* __restrict__ ob =
      outg + ((long)(bh >> 3) * HW + (long)y * WW) * DTOT + (bh & 7) * HD;

#define CONSV(S, sl)                                    \
  {                                                     \
    float o0[4], o1[4];                                 \
    _Pragma("unroll") for (int i = 0; i < 4; ++i) {     \
      const float t0l = tapL(b0##S[i]), t0r = tapR(b0##S[i]); \
      const float t1l = tapL(b1##S[i]), t1r = tapR(b1##S[i]); \
      const float t2l = tapL(b2##S[i]), t2r = tapR(b2##S[i]); \
      const float t3l = tapL(b3##S[i]), t3r = tapR(b3##S[i]); \
      float a = w[0] * t0l;                             \
      a = fmaf(w[1], b0##S[i], a);                      \
      a = fmaf(w[2], t0r, a);                           \
      a = fmaf(w[3], t1l, a);                           \
      a = fmaf(w[4], b1##S[i], a);                      \
      a = fmaf(w[5], t1r, a);                           \
      a = fmaf(w[6], t2l, a);                           \
      a = fmaf(w[7], b2##S[i], a);                      \
      a = fmaf(w[8], t2r, a);                           \
      o0[i] = a;                                        \
      float c = w[9] * t1l;                             \
      c = fmaf(w[10], b1##S[i], c);                     \
      c = fmaf(w[11], t1r, c);                          \
      c = fmaf(w[12], t2l, c);                          \
      c = fmaf(w[13], b2##S[i], c);                     \
      c = fmaf(w[14], t2r, c);                          \
      c = fmaf(w[15], t3l, c);                          \
      c = fmaf(w[16], b3##S[i], c);                     \
      c = fmaf(w[17], t3r, c);                          \
      o1[i] = c;                                        \
    }                                                   \
    *(float4*)&tbuf[l * TSTR + (sl) * 4] =              \
        make_float4(o0[0], o0[1], o0[2], o0[3]);        \
    *(float4*)&tbuf[(64 + l) * TSTR + (sl) * 4] =       \
        make_float4(o1[0], o1[1], o1[2], o1[3]);        \
  }
  // read-out of one 32-ch run for both rows: 112 px x 8 f4 = 14 exact rounds
#define READOUT(ch0)                                    \
  _Pragma("unroll") for (int r = 0; r < 14; ++r) {      \
    const int g = r * 64 + l;                           \
    const int pxl = g >> 3, slot = g & 7;               \
    const int lrow = pxl + ((pxl >= 56) ? 8 : 0);       \
    const float4 tv = *(const float4*)&tbuf[lrow * TSTR + slot * 4]; \
    *(float4*)(ob + (long)pxl * DTOT + (ch0) + slot * 4) = tv;      \
  }

  CONSV(A, 0); LOADV(A, 12);
  CONSV(B, 1); LOADV(B, 16);
  CONSV(C, 2); LOADV(C, 20);
  CONSV(A, 3); LOADV(A, 24);
  CONSV(B, 4); LOADV(B, 28);
  CONSV(C, 5); LOADV(C, 32);
  CONSV(A, 6); LOADV(A, 36);
  CONSV(B, 7); LOADV(B, 40);
  READOUT(0);
  CONSV(C, 0); LOADV(C, 44);
  CONSV(A, 1); LOADV(A, 48);
  CONSV(B, 2); LOADV(B, 52);
  CONSV(C, 3); LOADV(C, 56);
  CONSV(A, 4); LOADV(A, 60);
  CONSV(B, 5);
  CONSV(C, 6);
  CONSV(A, 7);
  READOUT(32);

#undef LOADK
#undef CONSK
#undef LOADV
#undef CONSV
#undef READOUT
}

} // namespace

extern "C" void kernel_launch(void* const* d_in, const int* in_sizes, int n_in,
                              void* d_out, int out_size, void* d_ws, size_t ws_size,
                              hipStream_t stream) {
  const float* q = (const float*)d_in[0];
  const float* k = (const float*)d_in[1];
  const float* v = (const float*)d_in[2];
  float* out = (float*)d_out;

  const int BH = in_sizes[0] / (HD * HW);  // B * 8 heads = 64
  dim3 grid(BH * NP);                       // 1792 = 8 * 224
  adda_fwd<<<grid, 128, 0, stream>>>(q, k, v, out);
}

// Round 25
// 33.629 us; speedup vs baseline: 16.3756x; 16.3756x over previous
//
#include <hip/hip_runtime.h>

// ADDA local attention, K=3, dilation=1, head_dim=64.
// q,k,v = [B=8, d=512, H=56, W=56] fp32 (channel-major), out = [B,H,W,512] fp32.
//
// R25 = R17 restored verbatim (session best: 33.58 us).
// Structure: wave = 2 output rows (y, y+1), lane = x. Per channel: 4 k-row
// + 2 q loads serve both rows; middle-row DPP taps shared. 4-channel slabs,
// 3 rotating register sets (2 slabs in flight per consume). v prologue
// issued before softmax. XCD-aware bijective swizzle. Wave owns each
// pixel's full 512B output run; TSTR=36 LDS transpose; full-128B-line
// stores; zero-padded-unfold masking at softmax only; no barriers.
//
// 24-round ledger: occupancy↑ (R13/R18/R21), wider loads (R20/R22), LDS
// staging (R7-R9), nt stores (R23), wave specialization (R24) all lose to
// this balance. Warm HBM traffic ~126 MB/replay is structural (L3 conflict
// misses on a 205 MB/replay working set vs 256 MB memory-side MALL).

namespace {

constexpr int HD = 64, HH = 56, WW = 56, HW = HH * WW;
constexpr int CS = HW, DTOT = 512;
constexpr float SCALE = 0.125f;
constexpr int NP   = HH / 2;   // 28 row-pairs
constexpr int TSTR = 36;       // px stride in transpose LDS

// value of this row at x-1 (lane i <- lane i-1): wave_shr:1 = 0x138
__device__ __forceinline__ float tapL(float v) {
  int i = __float_as_int(v);
  return __int_as_float(__builtin_amdgcn_update_dpp(i, i, 0x138, 0xF, 0xF, false));
}
// value of this row at x+1 (lane i <- lane i+1): wave_shl:1 = 0x130
__device__ __forceinline__ float tapR(float v) {
  int i = __float_as_int(v);
  return __int_as_float(__builtin_amdgcn_update_dpp(i, i, 0x130, 0xF, 0xF, false));
}

__global__ __launch_bounds__(64, 2)
void adda_fwd(const float* __restrict__ qg, const float* __restrict__ kg,
              const float* __restrict__ vg, float* __restrict__ outg) {
  __shared__ float tbuf[128 * TSTR];   // 18432 B (row y: 0..63, row y+1: 64..127)

  // XCD-aware bijective swizzle (nwg = 1792 = 8*224)
  int wg = (int)blockIdx.x;
  const int nwg = (int)gridDim.x;
  if ((nwg & 7) == 0) wg = (wg & 7) * (nwg >> 3) + (wg >> 3);

  const int pair = wg % NP;
  const int bh   = wg / NP;            // b*8 + head
  const int l    = (int)threadIdx.x;   // 0..63
  const int y    = pair * 2;           // rows y, y+1
  const int x    = l < WW ? l : WW - 1;  // lanes 56-63 clone x=55 (not stored)

  const long base = (long)bh * HD * HW;
  const int gy0 = (y > 0) ? y - 1 : 0;          // clamped; masked below
  const int gy3 = (y + 2 < HH) ? y + 2 : HH - 1;

  const float* __restrict__ qp0 = qg + base + (long)y * WW + x;
  const float* __restrict__ qp1 = qg + base + (long)(y + 1) * WW + x;
  const float* __restrict__ k0p = kg + base + (long)gy0 * WW + x;
  const float* __restrict__ k1p = kg + base + (long)y * WW + x;
  const float* __restrict__ k2p = kg + base + (long)(y + 1) * WW + x;
  const float* __restrict__ k3p = kg + base + (long)gy3 * WW + x;
  const float* __restrict__ v0p = vg + base + (long)gy0 * WW + x;
  const float* __restrict__ v1p = vg + base + (long)y * WW + x;
  const float* __restrict__ v2p = vg + base + (long)(y + 1) * WW + x;
  const float* __restrict__ v3p = vg + base + (long)gy3 * WW + x;

  float lg[18];
#pragma unroll
  for (int n = 0; n < 18; ++n) lg[n] = 0.f;

  // ---- 4-channel slabs, 3 rotating sets ----
  float q0A[4], q1A[4], a0A[4], a1A[4], a2A[4], a3A[4];
  float q0B[4], q1B[4], a0B[4], a1B[4], a2B[4], a3B[4];
  float q0C[4], q1C[4], a0C[4], a1C[4], a2C[4], a3C[4];

#define LOADK(S, cb)                                    \
  _Pragma("unroll") for (int i = 0; i < 4; ++i) {       \
    q0##S[i] = qp0[((cb) + i) * CS];                    \
    q1##S[i] = qp1[((cb) + i) * CS];                    \
    a0##S[i] = k0p[((cb) + i) * CS];                    \
    a1##S[i] = k1p[((cb) + i) * CS];                    \
    a2##S[i] = k2p[((cb) + i) * CS];                    \
    a3##S[i] = k3p[((cb) + i) * CS];                    \
  }
#define CONSK(S)                                        \
  _Pragma("unroll") for (int i = 0; i < 4; ++i) {       \
    const float t0l = tapL(a0##S[i]), t0r = tapR(a0##S[i]); \
    const float t1l = tapL(a1##S[i]), t1r = tapR(a1##S[i]); \
    const float t2l = tapL(a2##S[i]), t2r = tapR(a2##S[i]); \
    const float t3l = tapL(a3##S[i]), t3r = tapR(a3##S[i]); \
    const float q0 = q0##S[i], q1 = q1##S[i];           \
    lg[0]  = fmaf(q0, t0l,      lg[0]);                 \
    lg[1]  = fmaf(q0, a0##S[i], lg[1]);                 \
    lg[2]  = fmaf(q0, t0r,      lg[2]);                 \
    lg[3]  = fmaf(q0, t1l,      lg[3]);                 \
    lg[4]  = fmaf(q0, a1##S[i], lg[4]);                 \
    lg[5]  = fmaf(q0, t1r,      lg[5]);                 \
    lg[6]  = fmaf(q0, t2l,      lg[6]);                 \
    lg[7]  = fmaf(q0, a2##S[i], lg[7]);                 \
    lg[8]  = fmaf(q0, t2r,      lg[8]);                 \
    lg[9]  = fmaf(q1, t1l,      lg[9]);                 \
    lg[10] = fmaf(q1, a1##S[i], lg[10]);                \
    lg[11] = fmaf(q1, t1r,      lg[11]);                \
    lg[12] = fmaf(q1, t2l,      lg[12]);                \
    lg[13] = fmaf(q1, a2##S[i], lg[13]);                \
    lg[14] = fmaf(q1, t2r,      lg[14]);                \
    lg[15] = fmaf(q1, t3l,      lg[15]);                \
    lg[16] = fmaf(q1, a3##S[i], lg[16]);                \
    lg[17] = fmaf(q1, t3r,      lg[17]);                \
  }

  float b0A[4], b1A[4], b2A[4], b3A[4];
  float b0B[4], b1B[4], b2B[4], b3B[4];
  float b0C[4], b1C[4], b2C[4], b3C[4];
#define LOADV(S, cb)                                    \
  _Pragma("unroll") for (int i = 0; i < 4; ++i) {       \
    b0##S[i] = v0p[((cb) + i) * CS];                    \
    b1##S[i] = v1p[((cb) + i) * CS];                    \
    b2##S[i] = v2p[((cb) + i) * CS];                    \
    b3##S[i] = v3p[((cb) + i) * CS];                    \
  }

  // ---- pass 1: 16 k slabs, 3-deep ----
  LOADK(A, 0); LOADK(B, 4); LOADK(C, 8);
  CONSK(A); LOADK(A, 12);
  CONSK(B); LOADK(B, 16);
  CONSK(C); LOADK(C, 20);
  CONSK(A); LOADK(A, 24);
  CONSK(B); LOADK(B, 28);
  CONSK(C); LOADK(C, 32);
  CONSK(A); LOADK(A, 36);
  CONSK(B); LOADK(B, 40);
  CONSK(C); LOADK(C, 44);
  CONSK(A); LOADK(A, 48);
  CONSK(B); LOADK(B, 52);
  CONSK(C); LOADK(C, 56);
  CONSK(A); LOADK(A, 60);
  CONSK(B); LOADV(A, 0);
  CONSK(C); LOADV(B, 4);
  CONSK(A); LOADV(C, 8);

  // ---- softmax, both rows (zero-padded unfold: OOB logit = exact 0) ----
  const bool okl = x > 0, okr = x < WW - 1;
  const bool okt0 = y > 0;
  const bool okb1 = (y + 2) < HH;
  const bool ok[18] = {
    okt0 && okl, okt0, okt0 && okr,
    okl,         true, okr,
    okl,         true, okr,
    okl,         true, okr,
    okl,         true, okr,
    okb1 && okl, okb1, okb1 && okr};
  float w[18];
#pragma unroll
  for (int e = 0; e < 2; ++e) {
    float mx = 0.f;
#pragma unroll
    for (int n = 0; n < 9; ++n) {
      w[e * 9 + n] = ok[e * 9 + n] ? lg[e * 9 + n] * SCALE : 0.f;
      mx = fmaxf(mx, w[e * 9 + n]);
    }
    float sum = 0.f;
#pragma unroll
    for (int n = 0; n < 9; ++n) { w[e * 9 + n] = __expf(w[e * 9 + n] - mx); sum += w[e * 9 + n]; }
    const float inv = 1.f / sum;
#pragma unroll
    for (int n = 0; n < 9; ++n)
      w[e * 9 + n] = ok[e * 9 + n] ? w[e * 9 + n] * inv : 0.f;  // OOB v = 0
  }

  // ---- pass 2: 16 v slabs, 3-deep; per-slab f4 transpose store ----
  float* __restrict__ ob =
      outg + ((long)(bh >> 3) * HW + (long)y * WW) * DTOT + (bh & 7) * HD;

#define CONSV(S, sl)                                    \
  {                                                     \
    float o0[4], o1[4];                                 \
    _Pragma("unroll") for (int i = 0; i < 4; ++i) {     \
      const float t0l = tapL(b0##S[i]), t0r = tapR(b0##S[i]); \
      const float t1l = tapL(b1##S[i]), t1r = tapR(b1##S[i]); \
      const float t2l = tapL(b2##S[i]), t2r = tapR(b2##S[i]); \
      const float t3l = tapL(b3##S[i]), t3r = tapR(b3##S[i]); \
      float a = w[0] * t0l;                             \
      a = fmaf(w[1], b0##S[i], a);                      \
      a = fmaf(w[2], t0r, a);                           \
      a = fmaf(w[3], t1l, a);                           \
      a = fmaf(w[4], b1##S[i], a);                      \
      a = fmaf(w[5], t1r, a);                           \
      a = fmaf(w[6], t2l, a);                           \
      a = fmaf(w[7], b2##S[i], a);                      \
      a = fmaf(w[8], t2r, a);                           \
      o0[i] = a;                                        \
      float c = w[9] * t1l;                             \
      c = fmaf(w[10], b1##S[i], c);                     \
      c = fmaf(w[11], t1r, c);                          \
      c = fmaf(w[12], t2l, c);                          \
      c = fmaf(w[13], b2##S[i], c);                     \
      c = fmaf(w[14], t2r, c);                          \
      c = fmaf(w[15], t3l, c);                          \
      c = fmaf(w[16], b3##S[i], c);                     \
      c = fmaf(w[17], t3r, c);                          \
      o1[i] = c;                                        \
    }                                                   \
    *(float4*)&tbuf[l * TSTR + (sl) * 4] =              \
        make_float4(o0[0], o0[1], o0[2], o0[3]);        \
    *(float4*)&tbuf[(64 + l) * TSTR + (sl) * 4] =       \
        make_float4(o1[0], o1[1], o1[2], o1[3]);        \
  }
  // read-out of one 32-ch run for both rows: 112 px x 8 f4 = 14 exact rounds.
#define READOUT(ch0)                                    \
  _Pragma("unroll") for (int r = 0; r < 14; ++r) {      \
    const int g = r * 64 + l;                           \
    const int pxl = g >> 3, slot = g & 7;               \
    const int lrow = pxl + ((pxl >= 56) ? 8 : 0);       \
    const float4 tv = *(const float4*)&tbuf[lrow * TSTR + slot * 4]; \
    *(float4*)(ob + (long)pxl * DTOT + (ch0) + slot * 4) = tv;      \
  }

  CONSV(A, 0); LOADV(A, 12);
  CONSV(B, 1); LOADV(B, 16);
  CONSV(C, 2); LOADV(C, 20);
  CONSV(A, 3); LOADV(A, 24);
  CONSV(B, 4); LOADV(B, 28);
  CONSV(C, 5); LOADV(C, 32);
  CONSV(A, 6); LOADV(A, 36);
  CONSV(B, 7); LOADV(B, 40);
  READOUT(0);
  CONSV(C, 0); LOADV(C, 44);
  CONSV(A, 1); LOADV(A, 48);
  CONSV(B, 2); LOADV(B, 52);
  CONSV(C, 3); LOADV(C, 56);
  CONSV(A, 4); LOADV(A, 60);
  CONSV(B, 5);
  CONSV(C, 6);
  CONSV(A, 7);
  READOUT(32);

#undef LOADK
#undef CONSK
#undef LOADV
#undef CONSV
#undef READOUT
}

} // namespace

extern "C" void kernel_launch(void* const* d_in, const int* in_sizes, int n_in,
                              void* d_out, int out_size, void* d_ws, size_t ws_size,
                              hipStream_t stream) {
  const float* q = (const float*)d_in[0];
  const float* k = (const float*)d_in[1];
  const float* v = (const float*)d_in[2];
  float* out = (float*)d_out;

  const int BH = in_sizes[0] / (HD * HW);  // B * 8 heads = 64
  dim3 grid(BH * NP);                       // 1792 = 8 * 224
  adda_fwd<<<grid, 64, 0, stream>>>(q, k, v, out);
}